// Round 3
// baseline (208.522 us; speedup 1.0000x reference)
//
#include <hip/hip_runtime.h>

// Problem: B=8, S=512, NQ=12, L=4, 2^NQ = 4096 amplitudes.
// out = [psi_Q | psi_K | psi_V], each (B*S, 4096) fp32, concat flat.
// Single fused kernel: per block, build the 36 folded 2x2 unitaries
// (redundant per block — ~500 cycles, cheaper than a second launch + drain),
// then compute 2 samples' Q/K/V states via a kron tree in LDS and stream
// them out with nontemporal float4 stores (output is write-once, never read).

#define BS_TOTAL 4096   // B*S = 8*512
#define NQ 12
#define NL 4
#define NSTATE 4096     // 2^12
#define SPB 2           // samples per block

// native clang vector for __builtin_nontemporal_store (HIP float4 is a class)
typedef float vfloat4 __attribute__((ext_vector_type(4)));

__device__ __forceinline__ float2 cmul(float2 a, float2 b) {
    return make_float2(a.x * b.x - a.y * b.y, a.x * b.y + a.y * b.x);
}
__device__ __forceinline__ float2 cconj(float2 a) { return make_float2(a.x, -a.y); }
__device__ __forceinline__ float2 cadd(float2 a, float2 b) { return make_float2(a.x + b.x, a.y + b.y); }

__global__ __launch_bounds__(256) void vqc_fused_kernel(
    const float* __restrict__ angles,       // (B*S, 12)
    const float* __restrict__ tQ,           // (L, NQ, 3)
    const float* __restrict__ tK,
    const float* __restrict__ tV,
    float* __restrict__ out)                // (3, B*S, 4096)
{
    const int bs0 = blockIdx.x * SPB;
    const int t   = threadIdx.x;            // 0 .. 255

    __shared__ float2 Uu[3][NQ][4];         // folded unitaries     (1152 B)
    __shared__ float  cs[SPB][NQ][2];       // cos/sin(angle/2)     (192 B)
    __shared__ float2 vv[SPB][3][NQ][2];    // per-qubit 2-vectors  (1152 B)
    __shared__ float2 AB[SPB][3][2][16];    // qubits 0-3 / 4-7     (1536 B)
    __shared__ float2 Plo[SPB][3][16];      // qubits 8-11          (768 B)
    __shared__ float2 Phi[SPB][3][256];     // qubits 0-7           (12288 B)

    // ---- Phase A: fold layers into U (threads 0-35) + load angles (64-87) ----
    if (t < 36) {
        int m = t / NQ, n = t % NQ;
        const float* th = (m == 0) ? tQ : (m == 1) ? tK : tV;
        float2 U00 = {1.f, 0.f}, U01 = {0.f, 0.f}, U10 = {0.f, 0.f}, U11 = {1.f, 0.f};
#pragma unroll
        for (int l = 0; l < NL; ++l) {
            float c = 0.5f * th[(l * NQ + n) * 3 + 0];  // inner Rz
            float b = 0.5f * th[(l * NQ + n) * 3 + 1];  // Ry
            float a = 0.5f * th[(l * NQ + n) * 3 + 2];  // outer Rz
            float sa, ca, sb, cb, sc, cc;
            sincosf(a, &sa, &ca);
            sincosf(b, &sb, &cb);
            sincosf(c, &sc, &cc);
            float2 ea = {ca, -sa};                 // exp(-i a)
            float2 ec = {cc, -sc};                 // exp(-i c)
            float2 p  = cmul(ea, ec);
            float2 q  = cmul(ea, cconj(ec));
            float2 A00 = { cb * p.x,  cb * p.y};
            float2 A01 = {-sb * q.x, -sb * q.y};
            float2 A10 = { sb * q.x, -sb * q.y};   // sb * conj(q)
            float2 A11 = { cb * p.x, -cb * p.y};   // cb * conj(p)
            float2 n00 = cadd(cmul(A00, U00), cmul(A01, U10));
            float2 n01 = cadd(cmul(A00, U01), cmul(A01, U11));
            float2 n10 = cadd(cmul(A10, U00), cmul(A11, U10));
            float2 n11 = cadd(cmul(A10, U01), cmul(A11, U11));
            U00 = n00; U01 = n01; U10 = n10; U11 = n11;
        }
        Uu[m][n][0] = U00; Uu[m][n][1] = U01; Uu[m][n][2] = U10; Uu[m][n][3] = U11;
    } else if (t >= 64 && t < 64 + SPB * NQ) {
        int idx = t - 64, s2 = idx / NQ, n = idx % NQ;
        float a = angles[(bs0 + s2) * NQ + n];
        float s, c;
        sincosf(0.5f * a, &s, &c);
        cs[s2][n][0] = c; cs[s2][n][1] = s;
    }
    __syncthreads();

    // ---- Phase B: v = U @ [cos, sin]  (72 tasks) ----
    if (t < SPB * 36) {
        int s2 = t / 36, r = t % 36, m = r / NQ, n = r % NQ;
        float c = cs[s2][n][0], s = cs[s2][n][1];
        float2 u00 = Uu[m][n][0], u01 = Uu[m][n][1], u10 = Uu[m][n][2], u11 = Uu[m][n][3];
        vv[s2][m][n][0] = make_float2(u00.x * c + u01.x * s, u00.y * c + u01.y * s);
        vv[s2][m][n][1] = make_float2(u10.x * c + u11.x * s, u10.y * c + u11.y * s);
    }
    __syncthreads();

    // ---- Phase C: 4-qubit group products (288 tasks) ----
#pragma unroll
    for (int task = t; task < SPB * 144; task += 256) {
        int s2 = task / 144, r = task % 144, m = r / 48, g = (r % 48) / 16, idx = r % 16;
        int q0 = g * 4;
        float2 p = cmul(cmul(vv[s2][m][q0    ][(idx >> 3) & 1],
                             vv[s2][m][q0 + 1][(idx >> 2) & 1]),
                        cmul(vv[s2][m][q0 + 2][(idx >> 1) & 1],
                             vv[s2][m][q0 + 3][ idx       & 1]));
        if (g < 2) AB[s2][m][g][idx] = p; else Plo[s2][m][idx] = p;
    }
    __syncthreads();

    // ---- Phase D: Phi over qubits 0-7 (1536 tasks, 6/thread) ----
#pragma unroll
    for (int i = 0; i < 6; ++i) {
        int task = t + i * 256;
        int s2 = task / 768, r = task % 768, m = r / 256, e = r % 256;
        Phi[s2][m][e] = cmul(AB[s2][m][0][e >> 4], AB[s2][m][1][e & 15]);
    }
    __syncthreads();

    // ---- Phase E: emit amplitudes. k = j*1024 + t*4 + i:
    //      hi = k>>4 = j*64 + (t>>2), lo = 4*(t&3)+i ----
    const int lobase = 4 * (t & 3);
    const int hsub   = t >> 2;
#pragma unroll
    for (int s2 = 0; s2 < SPB; ++s2) {
#pragma unroll
        for (int m = 0; m < 3; ++m) {
            float2 l0 = Plo[s2][m][lobase + 0];
            float2 l1 = Plo[s2][m][lobase + 1];
            float2 l2 = Plo[s2][m][lobase + 2];
            float2 l3 = Plo[s2][m][lobase + 3];
            float* po = out + (size_t)m * BS_TOTAL * NSTATE + (size_t)(bs0 + s2) * NSTATE;
#pragma unroll
            for (int j = 0; j < 4; ++j) {
                float2 h = Phi[s2][m][j * 64 + hsub];
                vfloat4 r;
                r.x = h.x * l0.x - h.y * l0.y;   // Re(h * l)
                r.y = h.x * l1.x - h.y * l1.y;
                r.z = h.x * l2.x - h.y * l2.y;
                r.w = h.x * l3.x - h.y * l3.y;
                __builtin_nontemporal_store(r, (vfloat4*)(po + j * 1024 + t * 4));
            }
        }
    }
}

extern "C" void kernel_launch(void* const* d_in, const int* in_sizes, int n_in,
                              void* d_out, int out_size, void* d_ws, size_t ws_size,
                              hipStream_t stream) {
    (void)in_sizes; (void)n_in; (void)out_size; (void)d_ws; (void)ws_size;
    const float* angles = (const float*)d_in[0];   // (8,512,12)
    const float* tQ     = (const float*)d_in[1];   // (4,12,3)
    const float* tK     = (const float*)d_in[2];
    const float* tV     = (const float*)d_in[3];

    vqc_fused_kernel<<<BS_TOTAL / SPB, 256, 0, stream>>>(angles, tQ, tK, tV, (float*)d_out);
}

// Round 4
// 198.309 us; speedup vs baseline: 1.0515x; 1.0515x over previous
//
#include <hip/hip_runtime.h>

// Problem: B=8, S=512, NQ=12, L=4, 2^NQ = 4096 amplitudes.
// out = [psi_Q | psi_K | psi_V], each (B*S, 4096) fp32, concat flat.
//
// Single fused kernel, 4 samples/block, 3 barriers:
//  A1: 144 threads build per-layer Rz·Ry·Rz matrices (3 sincosf each);
//      48 threads sincos the angles.
//  A2: 36 threads fold 4 layers (3 complex 2x2 matmuls) -> U, then apply to
//      [cos,sin] for all 4 samples -> vv.
//  C : 4-qubit group products -> AB (qubits 0-3, 4-7), Plo (qubits 8-11).
//  E : each thread computes h = AB0 * AB1 in registers (wave-uniform /
//      broadcast LDS reads) and streams 48 coalesced float4 stores.
// Round-3 lesson: nontemporal stores cost ~5-10 us vs plain stores here.

#define BS_TOTAL 4096   // B*S = 8*512
#define NQ 12
#define NL 4
#define NSTATE 4096     // 2^12
#define SPB 4           // samples per block

__device__ __forceinline__ float2 cmul(float2 a, float2 b) {
    return make_float2(a.x * b.x - a.y * b.y, a.x * b.y + a.y * b.x);
}
__device__ __forceinline__ float2 cconj(float2 a) { return make_float2(a.x, -a.y); }
__device__ __forceinline__ float2 cadd(float2 a, float2 b) { return make_float2(a.x + b.x, a.y + b.y); }

__global__ __launch_bounds__(256) void vqc_fused_kernel(
    const float* __restrict__ angles,       // (B*S, 12)
    const float* __restrict__ tQ,           // (L, NQ, 3)
    const float* __restrict__ tK,
    const float* __restrict__ tV,
    float* __restrict__ out)                // (3, B*S, 4096)
{
    const int bs0 = blockIdx.x * SPB;
    const int t   = threadIdx.x;            // 0 .. 255

    __shared__ float2 Lm[36][NL][4];        // per-layer 2x2 matrices   (4608 B)
    __shared__ float  cs[SPB][NQ][2];       // cos/sin(angle/2)          (384 B)
    __shared__ float2 vv[SPB][3][NQ][2];    // per-qubit 2-vectors      (2304 B)
    __shared__ float2 AB[SPB][3][2][16];    // qubits 0-3 / 4-7         (3072 B)
    __shared__ float2 Plo[SPB][3][16];      // qubits 8-11              (1536 B)

    // ---- Phase A1: 144 threads build one layer matrix each; 48 load angles ----
    if (t < 144) {
        int l = t & 3, mn = t >> 2, m = mn / NQ, n = mn % NQ;
        const float* th = (m == 0) ? tQ : (m == 1) ? tK : tV;   // (L, NQ, 3)
        float c = 0.5f * th[(l * NQ + n) * 3 + 0];  // inner Rz
        float b = 0.5f * th[(l * NQ + n) * 3 + 1];  // Ry
        float a = 0.5f * th[(l * NQ + n) * 3 + 2];  // outer Rz
        float sa, ca, sb, cb, sc, cc;
        sincosf(a, &sa, &ca);
        sincosf(b, &sb, &cb);
        sincosf(c, &sc, &cc);
        float2 ea = {ca, -sa};                 // exp(-i a)
        float2 ec = {cc, -sc};                 // exp(-i c)
        float2 p  = cmul(ea, ec);
        float2 q  = cmul(ea, cconj(ec));
        Lm[mn][l][0] = make_float2( cb * p.x,  cb * p.y);
        Lm[mn][l][1] = make_float2(-sb * q.x, -sb * q.y);
        Lm[mn][l][2] = make_float2( sb * q.x, -sb * q.y);   // sb * conj(q)
        Lm[mn][l][3] = make_float2( cb * p.x, -cb * p.y);   // cb * conj(p)
    } else if (t >= 160 && t < 160 + SPB * NQ) {
        int idx = t - 160, s2 = idx / NQ, n = idx % NQ;
        float a = angles[(bs0 + s2) * NQ + n];
        float s, c;
        sincosf(0.5f * a, &s, &c);
        cs[s2][n][0] = c; cs[s2][n][1] = s;
    }
    __syncthreads();

    // ---- Phase A2: 36 threads fold 4 layers -> U, then vv for all samples ----
    if (t < 36) {
        int m = t / NQ, n = t % NQ;
        float2 U00 = Lm[t][0][0], U01 = Lm[t][0][1], U10 = Lm[t][0][2], U11 = Lm[t][0][3];
#pragma unroll
        for (int l = 1; l < NL; ++l) {
            float2 A00 = Lm[t][l][0], A01 = Lm[t][l][1], A10 = Lm[t][l][2], A11 = Lm[t][l][3];
            float2 n00 = cadd(cmul(A00, U00), cmul(A01, U10));
            float2 n01 = cadd(cmul(A00, U01), cmul(A01, U11));
            float2 n10 = cadd(cmul(A10, U00), cmul(A11, U10));
            float2 n11 = cadd(cmul(A10, U01), cmul(A11, U11));
            U00 = n00; U01 = n01; U10 = n10; U11 = n11;
        }
#pragma unroll
        for (int s2 = 0; s2 < SPB; ++s2) {
            float c = cs[s2][n][0], s = cs[s2][n][1];
            vv[s2][m][n][0] = make_float2(U00.x * c + U01.x * s, U00.y * c + U01.y * s);
            vv[s2][m][n][1] = make_float2(U10.x * c + U11.x * s, U10.y * c + U11.y * s);
        }
    }
    __syncthreads();

    // ---- Phase C: 4-qubit group products (SPB*144 = 576 tasks) ----
#pragma unroll
    for (int task = t; task < SPB * 144; task += 256) {
        int s2 = task / 144, r = task % 144, m = r / 48, g = (r % 48) / 16, idx = r % 16;
        int q0 = g * 4;
        float2 p = cmul(cmul(vv[s2][m][q0    ][(idx >> 3) & 1],
                             vv[s2][m][q0 + 1][(idx >> 2) & 1]),
                        cmul(vv[s2][m][q0 + 2][(idx >> 1) & 1],
                             vv[s2][m][q0 + 3][ idx       & 1]));
        if (g < 2) AB[s2][m][g][idx] = p; else Plo[s2][m][idx] = p;
    }
    __syncthreads();

    // ---- Phase E: k = j*1024 + t*4 + i; hi = j*4+(hsub>>4) (x) hsub&15;
    //      lo = 4*(t&3)+i. AB0 read is wave-uniform, AB1/Plo conflict-free. ----
    const int lobase = 4 * (t & 3);
    const int hsub   = t >> 2;
#pragma unroll
    for (int s2 = 0; s2 < SPB; ++s2) {
#pragma unroll
        for (int m = 0; m < 3; ++m) {
            float2 l0 = Plo[s2][m][lobase + 0];
            float2 l1 = Plo[s2][m][lobase + 1];
            float2 l2 = Plo[s2][m][lobase + 2];
            float2 l3 = Plo[s2][m][lobase + 3];
            float2 b1 = AB[s2][m][1][hsub & 15];
            float* po = out + (size_t)m * BS_TOTAL * NSTATE + (size_t)(bs0 + s2) * NSTATE;
#pragma unroll
            for (int j = 0; j < 4; ++j) {
                float2 h = cmul(AB[s2][m][0][j * 4 + (hsub >> 4)], b1);
                float4 r;
                r.x = h.x * l0.x - h.y * l0.y;   // Re(h * l)
                r.y = h.x * l1.x - h.y * l1.y;
                r.z = h.x * l2.x - h.y * l2.y;
                r.w = h.x * l3.x - h.y * l3.y;
                *(float4*)(po + j * 1024 + t * 4) = r;
            }
        }
    }
}

extern "C" void kernel_launch(void* const* d_in, const int* in_sizes, int n_in,
                              void* d_out, int out_size, void* d_ws, size_t ws_size,
                              hipStream_t stream) {
    (void)in_sizes; (void)n_in; (void)out_size; (void)d_ws; (void)ws_size;
    const float* angles = (const float*)d_in[0];   // (8,512,12)
    const float* tQ     = (const float*)d_in[1];   // (4,12,3)
    const float* tK     = (const float*)d_in[2];
    const float* tV     = (const float*)d_in[3];

    vqc_fused_kernel<<<BS_TOTAL / SPB, 256, 0, stream>>>(angles, tQ, tK, tV, (float*)d_out);
}